// Round 4
// baseline (709.590 us; speedup 1.0000x reference)
//
#include <hip/hip_runtime.h>
#include <hip/hip_bf16.h>

#define N_NODES 50000
#define N_EDGES 800000
#define NFEAT 512
#define NHID 128
#define NCLASS 40
#define BN_EPS 1e-5f

typedef __attribute__((ext_vector_type(8))) short short8;
typedef __attribute__((ext_vector_type(4))) float f32x4;

#define GEMM1_BLOCKS ((N_NODES + 127) / 128)   // 391 (BM=128 — proven best)
#define GEMMH_BLOCKS ((N_NODES + 127) / 128)   // 391
#define EDGE_BLOCKS ((N_EDGES + 255) / 256)    // 3125
#define SCAN_BLOCKS ((N_NODES + 255) / 256)    // 196
#define BN_BLOCKS ((N_NODES + 255) / 256)      // 196
#define AGG_BLOCKS ((N_NODES + 1) / 2)         // 25000 (2 nodes/block, 2 waves/node)

__device__ __forceinline__ unsigned short f2b(float f) {
    unsigned int u = __float_as_uint(f);
    u += 0x7fff + ((u >> 16) & 1);   // RTNE
    return (unsigned short)(u >> 16);
}
__device__ __forceinline__ unsigned int pk2(float lo, float hi) {
    unsigned int r;
    asm("v_cvt_pk_bf16_f32 %0, %1, %2" : "=v"(r) : "v"(lo), "v"(hi));
    return r;
}
__device__ __forceinline__ float blo(unsigned int v) {
    return __uint_as_float(v << 16);
}
__device__ __forceinline__ float bhi(unsigned int v) {
    return __uint_as_float(v & 0xffff0000u);
}

// ---------------------------------------------------------------------------
// Weight prep: fp32 W[K][128] -> bf16 W^T[128][K] for W1,W2,W3; zero degcnt,
// stats[768], sync[8].
__global__ void k_prep_w(const float* __restrict__ W1, const float* __restrict__ W2,
                         const float* __restrict__ W3, unsigned short* __restrict__ W1t,
                         unsigned short* __restrict__ W2t, unsigned short* __restrict__ W3t,
                         unsigned long long* __restrict__ degcnt,
                         float* __restrict__ stats, int* __restrict__ syncp) {
    int i = blockIdx.x * blockDim.x + threadIdx.x;
    if (i < N_NODES) degcnt[i] = 0ULL;
    if (i < 768) stats[i] = 0.f;
    else if (i < 776) syncp[i - 768] = 0;
    if (i < 65536) {
        int k = i >> 7, n = i & 127;
        W1t[n * 512 + k] = f2b(W1[i]);
    } else if (i < 81920) {
        int j = i - 65536; int k = j >> 7, n = j & 127;
        W2t[n * 128 + k] = f2b(W2[j]);
    } else if (i < 98304) {
        int j = i - 81920; int k = j >> 7, n = j & 127;
        W3t[n * 128 + k] = f2b(W3[j]);
    }
}

// ---------------------------------------------------------------------------
// FAT kernel: blocks [0,391) run layer-1 GEMM (BM=128 — R1-verified 62us);
// blocks [391, 391+3125) run edge convert+histogram.
__global__ __launch_bounds__(256) void k_fat(
    const float* __restrict__ x, const unsigned short* __restrict__ W1t,
    unsigned short* __restrict__ hbuf,
    const unsigned int* __restrict__ words, const float* __restrict__ ew,
    int* __restrict__ row, int* __restrict__ col,
    unsigned long long* __restrict__ degcnt, int* __restrict__ slot) {
    __shared__ unsigned short As[128][40];
    __shared__ unsigned short Bs[128][40];
    __shared__ int s_any;
    int tid = threadIdx.x;
    if (blockIdx.x < GEMM1_BLOCKS) {
        // ---- layer-1 GEMM: BM=128 BN=128 BK=32, K=512, prefetched ----
        int m0 = blockIdx.x * 128;
        int srow = tid >> 1;
        int skh = (tid & 1) << 4;
        int wave = tid >> 6, lane = tid & 63;
        int wm = (wave >> 1) * 64, wn = (wave & 1) * 64;
        int l15 = lane & 15, quad = lane >> 4;
        f32x4 acc[4][4] = {};
        bool arow_ok = (m0 + srow) < N_NODES;
        const float* arow_p = x + (size_t)(m0 + srow) * 512 + skh;
        const unsigned short* wrow_p = W1t + (size_t)srow * 512 + skh;
        float4 ta[4];
        uint4 tb0, tb1;
#pragma unroll
        for (int q = 0; q < 4; q++) {
            ta[q] = make_float4(0.f, 0.f, 0.f, 0.f);
            if (arow_ok) ta[q] = *(const float4*)(arow_p + q * 4);
        }
        tb0 = *(const uint4*)(wrow_p);
        tb1 = *(const uint4*)(wrow_p + 8);
        for (int kt = 0; kt < 512; kt += 32) {
            unsigned int p[8];
#pragma unroll
            for (int q = 0; q < 4; q++) {
                p[2 * q]     = pk2(ta[q].x, ta[q].y);
                p[2 * q + 1] = pk2(ta[q].z, ta[q].w);
            }
            *(uint4*)&As[srow][skh] = make_uint4(p[0], p[1], p[2], p[3]);
            *(uint4*)&As[srow][skh + 8] = make_uint4(p[4], p[5], p[6], p[7]);
            *(uint4*)&Bs[srow][skh] = tb0;
            *(uint4*)&Bs[srow][skh + 8] = tb1;
            __syncthreads();
            if (kt + 32 < 512) {   // prefetch next K-tile under ds_read+MFMA
#pragma unroll
                for (int q = 0; q < 4; q++) {
                    float4 t4 = make_float4(0.f, 0.f, 0.f, 0.f);
                    if (arow_ok) t4 = *(const float4*)(arow_p + kt + 32 + q * 4);
                    ta[q] = t4;
                }
                tb0 = *(const uint4*)(wrow_p + kt + 32);
                tb1 = *(const uint4*)(wrow_p + kt + 40);
            }
            short8 a[4], b[4];
#pragma unroll
            for (int i = 0; i < 4; i++) a[i] = *(const short8*)&As[wm + i * 16 + l15][quad * 8];
#pragma unroll
            for (int j = 0; j < 4; j++) b[j] = *(const short8*)&Bs[wn + j * 16 + l15][quad * 8];
#pragma unroll
            for (int i = 0; i < 4; i++)
#pragma unroll
                for (int j = 0; j < 4; j++)
                    acc[i][j] = __builtin_amdgcn_mfma_f32_16x16x32_bf16(a[i], b[j], acc[i][j], 0, 0, 0);
            __syncthreads();
        }
#pragma unroll
        for (int i = 0; i < 4; i++) {
            int mb = m0 + wm + i * 16 + quad * 4;
#pragma unroll
            for (int r = 0; r < 4; r++) {
                int m = mb + r;
                if (m < N_NODES) {
#pragma unroll
                    for (int j = 0; j < 4; j++)
                        hbuf[(size_t)m * 128 + wn + j * 16 + l15] = f2b(acc[i][j][r]);
                }
            }
        }
    } else {
        // ---- edge convert + degree histogram (per-block inline detect) ----
        if (tid == 0) s_any = 0;
        __syncthreads();
        unsigned int probe = words[2 * tid + 1];
        if (probe != 0) atomicAdd(&s_any, 1);
        __syncthreads();
        int f = (s_any == 0) ? 1 : 0;  // 1 => int64 layout
        int e = (blockIdx.x - GEMM1_BLOCKS) * 256 + tid;
        if (e < N_EDGES) {
            unsigned int r = f ? words[2 * (size_t)e] : words[e];
            unsigned int c = f ? words[2 * ((size_t)e + N_EDGES)] : words[e + N_EDGES];
            row[e] = (int)r;
            col[e] = (int)c;
            unsigned int q = __float2uint_rn(ew[e] * 8388608.0f);  // 2^23 fixed point
            unsigned long long old = atomicAdd(&degcnt[c], (1ULL << 32) | (unsigned long long)q);
            slot[e] = (int)(old >> 32);
        }
    }
}

// ---------------------------------------------------------------------------
// Fused graph-prep: dinv + per-block count reduce; ticket-last block scans the
// 196 block sums (scan2); spin barrier; per-block exclusive scan -> colptr
// (scan3); spin barrier; grid-stride scatter into ern. 196 blocks are always
// co-resident on 256 CUs -> spins are deadlock-safe. Extends the ticket
// pattern already HW-verified in R2/R3.
// sync: [0]=ticket  [1]=flagA (bpre ready)  [2]=flagB (colptr done count)
__global__ __launch_bounds__(256) void k_graph(
    const unsigned long long* __restrict__ degcnt,
    float* __restrict__ dinv, int* __restrict__ bsum,
    int* __restrict__ bpre, int* __restrict__ colptr,
    const int* __restrict__ row, const int* __restrict__ col,
    const float* __restrict__ ew, const int* __restrict__ slot,
    int2* __restrict__ ern, int* __restrict__ syncp) {
    int tid = threadIdx.x;
    int i = blockIdx.x * 256 + tid;
    __shared__ int sh[256];
    __shared__ int s_last;
    // ---- phase A: dinv + count, block reduce ----
    int cnt = 0;
    if (i < N_NODES) {
        unsigned long long v = degcnt[i];
        float deg = 1.0f + (float)(unsigned int)(v & 0xffffffffULL) * (1.0f / 8388608.0f);
        dinv[i] = rsqrtf(deg);
        cnt = (int)(v >> 32);
    }
    sh[tid] = cnt;
    __syncthreads();
    for (int ofs = 128; ofs > 0; ofs >>= 1) {
        if (tid < ofs) sh[tid] += sh[tid + ofs];
        __syncthreads();
    }
    if (tid == 0) {
        bsum[blockIdx.x] = sh[0];
        __threadfence();
        int t = atomicAdd(&syncp[0], 1);
        s_last = (t == SCAN_BLOCKS - 1) ? 1 : 0;
    }
    __syncthreads();
    if (s_last) {
        // scan2: scan the 196 block sums (all writers fenced above)
        __threadfence();
        int v = (tid < SCAN_BLOCKS) ? ((volatile int*)bsum)[tid] : 0;
        sh[tid] = v;
        __syncthreads();
        for (int ofs = 1; ofs < 256; ofs <<= 1) {
            int u = (tid >= ofs) ? sh[tid - ofs] : 0;
            __syncthreads();
            sh[tid] += u;
            __syncthreads();
        }
        if (tid < SCAN_BLOCKS) bpre[tid] = sh[tid] - v;  // exclusive
        if (tid == SCAN_BLOCKS - 1) colptr[N_NODES] = sh[tid];
        __threadfence();
        __syncthreads();
        if (tid == 0) atomicAdd(&syncp[1], 1);
    }
    // ---- wait for bpre ----
    if (tid == 0) {
        while (atomicAdd(&syncp[1], 0) == 0) __builtin_amdgcn_s_sleep(8);
    }
    __syncthreads();
    __threadfence();
    // ---- phase B: scan3 (exclusive scan of this block's counts) ----
    sh[tid] = cnt;
    __syncthreads();
    for (int ofs = 1; ofs < 256; ofs <<= 1) {
        int u = (tid >= ofs) ? sh[tid - ofs] : 0;
        __syncthreads();
        sh[tid] += u;
        __syncthreads();
    }
    if (i < N_NODES) colptr[i] = bpre[blockIdx.x] + sh[tid] - cnt;
    __threadfence();
    if (tid == 0) {
        atomicAdd(&syncp[2], 1);
        while (atomicAdd(&syncp[2], 0) < SCAN_BLOCKS) __builtin_amdgcn_s_sleep(8);
    }
    __syncthreads();
    __threadfence();
    // ---- phase C: scatter (grid-stride over edges) ----
#pragma unroll 4
    for (int e = i; e < N_EDGES; e += SCAN_BLOCKS * 256) {
        int c = col[e], r = row[e];
        int p = colptr[c] + slot[e];
        float nrm = dinv[r] * ew[e] * dinv[c];
        ern[p] = make_int2(r, __float_as_int(nrm));
    }
}

// ---------------------------------------------------------------------------
// CSR aggregation: TWO waves per node, 8-edge chunks alternating between the
// wave pair, with next-chunk ern prefetch pipelined under the gather+FMA.
__global__ __launch_bounds__(256) void k_aggregate(
    const unsigned int* __restrict__ hb, const int* __restrict__ colptr,
    const int2* __restrict__ ern, const float* __restrict__ dinv,
    const float* __restrict__ bias, unsigned int* __restrict__ out, int relu) {
    int wave = threadIdx.x >> 6;
    int lane = threadIdx.x & 63;
    int node = blockIdx.x * 2 + (wave >> 1);
    int half = wave & 1;
    float a0 = 0.f, a1 = 0.f, c0 = 0.f, c1 = 0.f;
    if (node < N_NODES) {
        int start = colptr[node], end = colptr[node + 1];
        if (half == 0) {
            float di = dinv[node];
            float selfw = di * di;
            unsigned int sv = hb[(size_t)node * 64 + lane];
            a0 = selfw * blo(sv);
            a1 = selfw * bhi(sv);
        }
        int e = start + half * 8;
        if (e + 8 <= end) {
            int2 rwc[8];
#pragma unroll
            for (int q = 0; q < 8; q++) rwc[q] = ern[e + q];
            for (;;) {
                int en = e + 16;
                bool more = (en + 8 <= end);
                int2 rwn[8];
                if (more) {
#pragma unroll
                    for (int q = 0; q < 8; q++) rwn[q] = ern[en + q];  // prefetch
                }
                unsigned int v[8];
#pragma unroll
                for (int q = 0; q < 8; q++) v[q] = hb[(size_t)rwc[q].x * 64 + lane];
#pragma unroll
                for (int q = 0; q < 8; q++) {
                    float w = __int_as_float(rwc[q].y);
                    if (q & 1) { c0 += w * blo(v[q]); c1 += w * bhi(v[q]); }
                    else       { a0 += w * blo(v[q]); a1 += w * bhi(v[q]); }
                }
                if (!more) break;
#pragma unroll
                for (int q = 0; q < 8; q++) rwc[q] = rwn[q];
                e = en;
            }
        }
        // tail (<8 edges) belongs to the wave whose chunk parity matches
        int nc = (end - start) >> 3;
        if (half == (nc & 1)) {
            for (int t = start + nc * 8; t < end; t++) {
                int2 rw = ern[t];
                float w = __int_as_float(rw.y);
                unsigned int v = hb[(size_t)rw.x * 64 + lane];
                a0 += w * blo(v);
                a1 += w * bhi(v);
            }
        }
    }
    __shared__ float red[4][64][2];
    red[wave][lane][0] = a0 + c0;
    red[wave][lane][1] = a1 + c1;
    __syncthreads();
    if (half == 0 && node < N_NODES) {
        float r0 = red[wave][lane][0] + red[wave + 1][lane][0];
        float r1 = red[wave][lane][1] + red[wave + 1][lane][1];
        float2 bv = *(const float2*)&bias[2 * lane];
        r0 += bv.x;
        r1 += bv.y;
        if (relu) { r0 = fmaxf(r0, 0.f); r1 = fmaxf(r1, 0.f); }
        out[(size_t)node * 64 + lane] = pk2(r0, r1);
    }
}

// ---------------------------------------------------------------------------
// BatchNorm stats (layer 3 only; layers 1-2 are fused into k_gemm_h).
__global__ __launch_bounds__(256) void k_bnstats(const unsigned int* __restrict__ x,
                                                 float* __restrict__ sums,
                                                 float* __restrict__ sumsq) {
    int u = threadIdx.x & 63;
    int strip = threadIdx.x >> 6;
    int r0 = blockIdx.x * 256;
    int rend = min(r0 + 256, N_NODES);
    float sl = 0.f, s2l = 0.f, sh_ = 0.f, s2h = 0.f;
    for (int r = r0 + strip; r < rend; r += 4) {
        unsigned int v = x[(size_t)r * 64 + u];
        float a = blo(v), b = bhi(v);
        sl += a; s2l += a * a;
        sh_ += b; s2h += b * b;
    }
    __shared__ float buf[4][64][4];
    buf[strip][u][0] = sl; buf[strip][u][1] = s2l;
    buf[strip][u][2] = sh_; buf[strip][u][3] = s2h;
    __syncthreads();
    if (strip == 0) {
#pragma unroll
        for (int s = 1; s < 4; s++) {
            sl += buf[s][u][0]; s2l += buf[s][u][1];
            sh_ += buf[s][u][2]; s2h += buf[s][u][3];
        }
        atomicAdd(&sums[2 * u], sl);
        atomicAdd(&sums[2 * u + 1], sh_);
        atomicAdd(&sumsq[2 * u], s2l);
        atomicAdd(&sumsq[2 * u + 1], s2h);
    }
}

// ---------------------------------------------------------------------------
// Layer-2/3 GEMM with FUSED BN stats: phase 1 computes this block's own
// M-tile stats -> atomics -> all-block spin barrier (391 blocks, >=5
// blocks/CU co-residency margin) -> phase 2 applies BN inline + GEMM.
__global__ __launch_bounds__(256) void k_gemm_h(
    const unsigned int* __restrict__ Ab, const unsigned short* __restrict__ Wt,
    float* __restrict__ sums, float* __restrict__ sumsq,
    const float* __restrict__ g, const float* __restrict__ be,
    unsigned short* __restrict__ Out, int* __restrict__ bar) {
    __shared__ unsigned short As[128][40];
    __shared__ unsigned short Bs[128][40];
    __shared__ float s_sc[128], s_sh[128];
    __shared__ float redbuf[4][64][4];
    int tid = threadIdx.x;
    int m0 = blockIdx.x * 128;
    // ---- phase 1: BN stats over this block's own M-tile ----
    {
        int u = tid & 63, strip = tid >> 6;
        int rend = min(m0 + 128, N_NODES);
        float sl = 0.f, s2l = 0.f, shh = 0.f, s2h = 0.f;
        for (int r = m0 + strip; r < rend; r += 4) {
            unsigned int v = Ab[(size_t)r * 64 + u];
            float a = blo(v), b = bhi(v);
            sl += a; s2l += a * a;
            shh += b; s2h += b * b;
        }
        redbuf[strip][u][0] = sl; redbuf[strip][u][1] = s2l;
        redbuf[strip][u][2] = shh; redbuf[strip][u][3] = s2h;
        __syncthreads();
        if (strip == 0) {
#pragma unroll
            for (int s = 1; s < 4; s++) {
                sl += redbuf[s][u][0]; s2l += redbuf[s][u][1];
                shh += redbuf[s][u][2]; s2h += redbuf[s][u][3];
            }
            atomicAdd(&sums[2 * u], sl);
            atomicAdd(&sums[2 * u + 1], shh);
            atomicAdd(&sumsq[2 * u], s2l);
            atomicAdd(&sumsq[2 * u + 1], s2h);
        }
        __syncthreads();
        if (tid == 0) {
            __threadfence();
            atomicAdd(bar, 1);
            while (atomicAdd(bar, 0) < GEMMH_BLOCKS) __builtin_amdgcn_s_sleep(8);
        }
        __syncthreads();
        __threadfence();
    }
    // ---- phase 2: BN apply inline + GEMM (K=128, prefetched) ----
    if (tid < 128) {
        const float invn = 1.0f / (float)N_NODES;
        float mu = sums[tid] * invn;
        float var = sumsq[tid] * invn - mu * mu;
        float iv = rsqrtf(var + BN_EPS);
        float sc = g[tid] * iv;
        s_sc[tid] = sc;
        s_sh[tid] = be[tid] - mu * sc;
    }
    __syncthreads();
    int srow = tid >> 1;
    int skh = (tid & 1) << 4;
    int wave = tid >> 6, lane = tid & 63;
    int wm = (wave >> 1) * 64, wn = (wave & 1) * 64;
    int l15 = lane & 15, quad = lane >> 4;
    f32x4 acc[4][4] = {};
    bool arow_ok = (m0 + srow) < N_NODES;
    const unsigned int* arow_b = Ab + (size_t)(m0 + srow) * 64 + (skh >> 1);
    const unsigned short* wrow_p = Wt + (size_t)srow * 128 + skh;
    uint4 r0 = make_uint4(0, 0, 0, 0), r1 = make_uint4(0, 0, 0, 0);
    uint4 tb0, tb1;
    if (arow_ok) {
        r0 = *(const uint4*)(arow_b);
        r1 = *(const uint4*)(arow_b + 4);
    }
    tb0 = *(const uint4*)(wrow_p);
    tb1 = *(const uint4*)(wrow_p + 8);
    for (int kt = 0; kt < 128; kt += 32) {
        unsigned int raw[8] = {r0.x, r0.y, r0.z, r0.w, r1.x, r1.y, r1.z, r1.w};
        unsigned int p[8];
#pragma unroll
        for (int q = 0; q < 8; q++) {
            int ch = kt + skh + 2 * q;
            float f0 = blo(raw[q]) * s_sc[ch] + s_sh[ch];
            float f1 = bhi(raw[q]) * s_sc[ch + 1] + s_sh[ch + 1];
            p[q] = pk2(f0, f1);
        }
        *(uint4*)&As[srow][skh] = make_uint4(p[0], p[1], p[2], p[3]);
        *(uint4*)&As[srow][skh + 8] = make_uint4(p[4], p[5], p[6], p[7]);
        *(uint4*)&Bs[srow][skh] = tb0;
        *(uint4*)&Bs[srow][skh + 8] = tb1;
        __syncthreads();
        if (kt + 32 < 128) {   // prefetch next K-tile under ds_read+MFMA
            if (arow_ok) {
                r0 = *(const uint4*)(arow_b + ((kt + 32) >> 1));
                r1 = *(const uint4*)(arow_b + ((kt + 32) >> 1) + 4);
            }
            tb0 = *(const uint4*)(wrow_p + kt + 32);
            tb1 = *(const uint4*)(wrow_p + kt + 40);
        }
        short8 a[4], b[4];
#pragma unroll
        for (int i = 0; i < 4; i++) a[i] = *(const short8*)&As[wm + i * 16 + l15][quad * 8];
#pragma unroll
        for (int j = 0; j < 4; j++) b[j] = *(const short8*)&Bs[wn + j * 16 + l15][quad * 8];
#pragma unroll
        for (int i = 0; i < 4; i++)
#pragma unroll
            for (int j = 0; j < 4; j++)
                acc[i][j] = __builtin_amdgcn_mfma_f32_16x16x32_bf16(a[i], b[j], acc[i][j], 0, 0, 0);
        __syncthreads();
    }
#pragma unroll
    for (int i = 0; i < 4; i++) {
        int mb = m0 + wm + i * 16 + quad * 4;
#pragma unroll
        for (int r = 0; r < 4; r++) {
            int m = mb + r;
            if (m < N_NODES) {
#pragma unroll
                for (int j = 0; j < 4; j++)
                    Out[(size_t)m * 128 + wn + j * 16 + l15] = f2b(acc[i][j][r]);
            }
        }
    }
}

// ---------------------------------------------------------------------------
// Head: BN3 scale/shift from raw sums (inline), x3 fp32 write, logits+softmax.
__global__ __launch_bounds__(256) void k_logits(const unsigned int* __restrict__ abuf,
                                                const float* __restrict__ sums,
                                                const float* __restrict__ sumsq,
                                                const float* __restrict__ g,
                                                const float* __restrict__ be,
                                                const float* __restrict__ linW,
                                                const float* __restrict__ linb,
                                                float* __restrict__ logits,
                                                float* __restrict__ probs,
                                                float* __restrict__ x3out) {
    __shared__ float Xs[64][130];
    __shared__ float Ws[128 * 40];
    __shared__ float s_sc[128], s_sh[128];
    int tid = threadIdx.x;
    int m0 = blockIdx.x * 64;
    if (tid < 128) {
        const float invn = 1.0f / (float)N_NODES;
        float mu = sums[tid] * invn;
        float var = sumsq[tid] * invn - mu * mu;
        float iv = rsqrtf(var + BN_EPS);
        float sc = g[tid] * iv;
        s_sc[tid] = sc;
        s_sh[tid] = be[tid] - mu * sc;
    }
    for (int q = tid; q < 1280; q += 256)
        *(float4*)&Ws[q * 4] = *(const float4*)&linW[q * 4];
    __syncthreads();
    for (int q = tid; q < 4096; q += 256) {
        int r = q >> 6, u = q & 63;
        int m = m0 + r;
        float f0 = 0.f, f1 = 0.f;
        if (m < N_NODES) {
            unsigned int v = abuf[(size_t)m * 64 + u];
            f0 = blo(v) * s_sc[2 * u] + s_sh[2 * u];
            f1 = bhi(v) * s_sc[2 * u + 1] + s_sh[2 * u + 1];
            *(float2*)&x3out[(size_t)m * 128 + 2 * u] = make_float2(f0, f1);
        }
        *(float2*)&Xs[r][2 * u] = make_float2(f0, f1);
    }
    __syncthreads();
    int r = tid >> 2;
    int cg = tid & 3;
    int cbase = cg * 10;
    float acc[10] = {};
    for (int k = 0; k < 128; k++) {
        float a = Xs[r][k];
#pragma unroll
        for (int j = 0; j < 10; j++) acc[j] += a * Ws[k * 40 + cbase + j];
    }
#pragma unroll
    for (int j = 0; j < 10; j++) acc[j] += linb[cbase + j];
    float m = acc[0];
#pragma unroll
    for (int j = 1; j < 10; j++) m = fmaxf(m, acc[j]);
    m = fmaxf(m, __shfl_xor(m, 1));
    m = fmaxf(m, __shfl_xor(m, 2));
    float ex[10];
    float s = 0.f;
#pragma unroll
    for (int j = 0; j < 10; j++) { ex[j] = expf(acc[j] - m); s += ex[j]; }
    s += __shfl_xor(s, 1);
    s += __shfl_xor(s, 2);
    float inv = 1.0f / s;
    int mrow = m0 + r;
    if (mrow < N_NODES) {
#pragma unroll
        for (int j = 0; j < 10; j += 2) {
            *(float2*)&logits[(size_t)mrow * 40 + cbase + j] = make_float2(acc[j], acc[j + 1]);
            *(float2*)&probs[(size_t)mrow * 40 + cbase + j] = make_float2(ex[j] * inv, ex[j + 1] * inv);
        }
    }
}

// ---------------------------------------------------------------------------
extern "C" void kernel_launch(void* const* d_in, const int* in_sizes, int n_in,
                              void* d_out, int out_size, void* d_ws, size_t ws_size,
                              hipStream_t stream) {
    const float* x = (const float*)d_in[0];
    const unsigned int* eidx = (const unsigned int*)d_in[1];
    const float* ew = (const float*)d_in[2];
    const float* W1 = (const float*)d_in[3];
    const float* b1 = (const float*)d_in[4];
    const float* W2 = (const float*)d_in[5];
    const float* b2 = (const float*)d_in[6];
    const float* W3 = (const float*)d_in[7];
    const float* b3 = (const float*)d_in[8];
    const float* g1 = (const float*)d_in[9];
    const float* be1 = (const float*)d_in[10];
    const float* g2 = (const float*)d_in[11];
    const float* be2 = (const float*)d_in[12];
    const float* g3 = (const float*)d_in[13];
    const float* be3 = (const float*)d_in[14];
    const float* linW = (const float*)d_in[15];
    const float* linb = (const float*)d_in[16];

    float* out = (float*)d_out;
    float* logits = out;
    float* probs = out + (size_t)N_NODES * NCLASS;
    float* x3out = out + 2 * (size_t)N_NODES * NCLASS;

    char* ws = (char*)d_ws;
    size_t off = 0;
    auto take = [&](size_t bytes) -> char* {
        char* p = ws + off;
        off += (bytes + 255) & ~(size_t)255;
        return p;
    };
    int* row32 = (int*)take((size_t)N_EDGES * 4);
    int* col32 = (int*)take((size_t)N_EDGES * 4);
    int* slot = (int*)take((size_t)N_EDGES * 4);
    int* colptr = (int*)take((size_t)(N_NODES + 1) * 4);
    unsigned long long* degcnt = (unsigned long long*)take((size_t)N_NODES * 8);
    int2* ern = (int2*)take((size_t)N_EDGES * 8);
    float* dinv = (float*)take((size_t)N_NODES * 4);
    unsigned short* hbuf = (unsigned short*)take((size_t)N_NODES * NHID * 2);
    unsigned short* abuf = (unsigned short*)take((size_t)N_NODES * NHID * 2);
    unsigned short* W1t = (unsigned short*)take((size_t)512 * 128 * 2);
    unsigned short* W2t = (unsigned short*)take((size_t)128 * 128 * 2);
    unsigned short* W3t = (unsigned short*)take((size_t)128 * 128 * 2);
    float* stats = (float*)take(768 * 4);   // [sums1|sumsq1|sums2|sumsq2|sums3|sumsq3]
    int* syncp = (int*)take(8 * 4);         // [ticket, flagA, flagB, bar2, bar3, ...]
    int* bsum = (int*)take((size_t)SCAN_BLOCKS * 4);
    int* bpre = (int*)take((size_t)SCAN_BLOCKS * 4);
    (void)ws_size; (void)n_in; (void)in_sizes; (void)out_size;

    float* sums1 = stats, *sumsq1 = stats + 128;
    float* sums2 = stats + 256, *sumsq2 = stats + 384;
    float* sums3 = stats + 512, *sumsq3 = stats + 640;

    const int TPB = 256;

    // preprocessing + layer-1 GEMM overlapped with edge histogram
    k_prep_w<<<(98304 + TPB - 1) / TPB, TPB, 0, stream>>>(W1, W2, W3, W1t, W2t, W3t, degcnt, stats, syncp);
    k_fat<<<GEMM1_BLOCKS + EDGE_BLOCKS, TPB, 0, stream>>>(
        x, W1t, hbuf, eidx, ew, row32, col32, degcnt, slot);
    k_graph<<<SCAN_BLOCKS, TPB, 0, stream>>>(degcnt, dinv, bsum, bpre, colptr,
                                             row32, col32, ew, slot, ern, syncp);

    // layer 1 -> layer 2 (BN1 stats fused into gemm phase 1)
    k_aggregate<<<AGG_BLOCKS, TPB, 0, stream>>>((const unsigned int*)hbuf, colptr, ern, dinv, b1, (unsigned int*)abuf, 1);
    k_gemm_h<<<GEMMH_BLOCKS, TPB, 0, stream>>>((const unsigned int*)abuf, W2t, sums1, sumsq1, g1, be1, hbuf, &syncp[3]);

    // layer 2 -> layer 3
    k_aggregate<<<AGG_BLOCKS, TPB, 0, stream>>>((const unsigned int*)hbuf, colptr, ern, dinv, b2, (unsigned int*)abuf, 1);
    k_gemm_h<<<GEMMH_BLOCKS, TPB, 0, stream>>>((const unsigned int*)abuf, W3t, sums2, sumsq2, g2, be2, hbuf, &syncp[4]);

    // layer 3
    k_aggregate<<<AGG_BLOCKS, TPB, 0, stream>>>((const unsigned int*)hbuf, colptr, ern, dinv, b3, (unsigned int*)abuf, 0);
    k_bnstats<<<BN_BLOCKS, TPB, 0, stream>>>((const unsigned int*)abuf, sums3, sumsq3);

    // head: BN3 apply (inline) + x3 write + logits + softmax
    k_logits<<<(N_NODES + 63) / 64, TPB, 0, stream>>>((const unsigned int*)abuf, sums3, sumsq3, g3, be3, linW, linb, logits, probs, x3out);
}

// Round 6
// 547.076 us; speedup vs baseline: 1.2971x; 1.2971x over previous
//
#include <hip/hip_runtime.h>
#include <hip/hip_bf16.h>

#define N_NODES 50000
#define N_EDGES 800000
#define NFEAT 512
#define NHID 128
#define NCLASS 40
#define BN_EPS 1e-5f

typedef __attribute__((ext_vector_type(8))) short short8;
typedef __attribute__((ext_vector_type(4))) float f32x4;

#define GEMM1_BLOCKS ((N_NODES + 127) / 128)   // 391 (BM=128 — proven best)
#define GEMMH_BLOCKS ((N_NODES + 127) / 128)   // 391
#define EDGE_BLOCKS ((N_EDGES + 255) / 256)    // 3125
#define SCAN_BLOCKS ((N_NODES + 255) / 256)    // 196
#define BN_BLOCKS ((N_NODES + 255) / 256)      // 196
#define AGG_BLOCKS ((N_NODES * 64 + 255) / 256) // 12500 (1 wave per node)

__device__ __forceinline__ unsigned short f2b(float f) {
    unsigned int u = __float_as_uint(f);
    u += 0x7fff + ((u >> 16) & 1);   // RTNE
    return (unsigned short)(u >> 16);
}
__device__ __forceinline__ unsigned int pk2(float lo, float hi) {
    unsigned int r;
    asm("v_cvt_pk_bf16_f32 %0, %1, %2" : "=v"(r) : "v"(lo), "v"(hi));
    return r;
}
__device__ __forceinline__ float blo(unsigned int v) {
    return __uint_as_float(v << 16);
}
__device__ __forceinline__ float bhi(unsigned int v) {
    return __uint_as_float(v & 0xffff0000u);
}

// ---------------------------------------------------------------------------
// Weight prep: fp32 W[K][128] -> bf16 W^T[128][K] for W1,W2,W3; zero degcnt,
// stats[768], sync[8].
__global__ void k_prep_w(const float* __restrict__ W1, const float* __restrict__ W2,
                         const float* __restrict__ W3, unsigned short* __restrict__ W1t,
                         unsigned short* __restrict__ W2t, unsigned short* __restrict__ W3t,
                         unsigned long long* __restrict__ degcnt,
                         float* __restrict__ stats, int* __restrict__ syncp) {
    int i = blockIdx.x * blockDim.x + threadIdx.x;
    if (i < N_NODES) degcnt[i] = 0ULL;
    if (i < 768) stats[i] = 0.f;
    else if (i < 776) syncp[i - 768] = 0;
    if (i < 65536) {
        int k = i >> 7, n = i & 127;
        W1t[n * 512 + k] = f2b(W1[i]);
    } else if (i < 81920) {
        int j = i - 65536; int k = j >> 7, n = j & 127;
        W2t[n * 128 + k] = f2b(W2[j]);
    } else if (i < 98304) {
        int j = i - 81920; int k = j >> 7, n = j & 127;
        W3t[n * 128 + k] = f2b(W3[j]);
    }
}

// ---------------------------------------------------------------------------
// Edge convert + degree histogram. SPLIT from the old fat kernel: its 12.5K
// waves of pure memory+atomic traffic congested the GEMM's load latency
// (R4 evidence: fat kernel 62us with all utilizations <5%).
__global__ __launch_bounds__(256) void k_edges(
    const unsigned int* __restrict__ words, const float* __restrict__ ew,
    int* __restrict__ row, int* __restrict__ col,
    unsigned long long* __restrict__ degcnt, int* __restrict__ slot) {
    __shared__ int s_any;
    int tid = threadIdx.x;
    if (tid == 0) s_any = 0;
    __syncthreads();
    unsigned int probe = words[2 * tid + 1];
    if (probe != 0) atomicAdd(&s_any, 1);
    __syncthreads();
    int f = (s_any == 0) ? 1 : 0;  // 1 => int64 layout
    int e = blockIdx.x * 256 + tid;
    if (e < N_EDGES) {
        unsigned int r = f ? words[2 * (size_t)e] : words[e];
        unsigned int c = f ? words[2 * ((size_t)e + N_EDGES)] : words[e + N_EDGES];
        row[e] = (int)r;
        col[e] = (int)c;
        unsigned int q = __float2uint_rn(ew[e] * 8388608.0f);  // 2^23 fixed point
        unsigned long long old = atomicAdd(&degcnt[c], (1ULL << 32) | (unsigned long long)q);
        slot[e] = (int)(old >> 32);
    }
}

// ---------------------------------------------------------------------------
// Layer-1 GEMM: x fp32 @ W1 -> hbuf bf16. BM=128 BN=128 BK=32, K=512,
// global->reg prefetch across the barrier.
__global__ __launch_bounds__(256) void k_gemm1(
    const float* __restrict__ x, const unsigned short* __restrict__ W1t,
    unsigned short* __restrict__ hbuf) {
    __shared__ unsigned short As[128][40];
    __shared__ unsigned short Bs[128][40];
    int tid = threadIdx.x;
    int m0 = blockIdx.x * 128;
    int srow = tid >> 1;
    int skh = (tid & 1) << 4;
    int wave = tid >> 6, lane = tid & 63;
    int wm = (wave >> 1) * 64, wn = (wave & 1) * 64;
    int l15 = lane & 15, quad = lane >> 4;
    f32x4 acc[4][4] = {};
    bool arow_ok = (m0 + srow) < N_NODES;
    const float* arow_p = x + (size_t)(m0 + srow) * 512 + skh;
    const unsigned short* wrow_p = W1t + (size_t)srow * 512 + skh;
    float4 ta[4];
    uint4 tb0, tb1;
#pragma unroll
    for (int q = 0; q < 4; q++) {
        ta[q] = make_float4(0.f, 0.f, 0.f, 0.f);
        if (arow_ok) ta[q] = *(const float4*)(arow_p + q * 4);
    }
    tb0 = *(const uint4*)(wrow_p);
    tb1 = *(const uint4*)(wrow_p + 8);
    for (int kt = 0; kt < 512; kt += 32) {
        unsigned int p[8];
#pragma unroll
        for (int q = 0; q < 4; q++) {
            p[2 * q]     = pk2(ta[q].x, ta[q].y);
            p[2 * q + 1] = pk2(ta[q].z, ta[q].w);
        }
        *(uint4*)&As[srow][skh] = make_uint4(p[0], p[1], p[2], p[3]);
        *(uint4*)&As[srow][skh + 8] = make_uint4(p[4], p[5], p[6], p[7]);
        *(uint4*)&Bs[srow][skh] = tb0;
        *(uint4*)&Bs[srow][skh + 8] = tb1;
        __syncthreads();
        if (kt + 32 < 512) {   // prefetch next K-tile under ds_read+MFMA
#pragma unroll
            for (int q = 0; q < 4; q++) {
                float4 t4 = make_float4(0.f, 0.f, 0.f, 0.f);
                if (arow_ok) t4 = *(const float4*)(arow_p + kt + 32 + q * 4);
                ta[q] = t4;
            }
            tb0 = *(const uint4*)(wrow_p + kt + 32);
            tb1 = *(const uint4*)(wrow_p + kt + 40);
        }
        short8 a[4], b[4];
#pragma unroll
        for (int i = 0; i < 4; i++) a[i] = *(const short8*)&As[wm + i * 16 + l15][quad * 8];
#pragma unroll
        for (int j = 0; j < 4; j++) b[j] = *(const short8*)&Bs[wn + j * 16 + l15][quad * 8];
#pragma unroll
        for (int i = 0; i < 4; i++)
#pragma unroll
            for (int j = 0; j < 4; j++)
                acc[i][j] = __builtin_amdgcn_mfma_f32_16x16x32_bf16(a[i], b[j], acc[i][j], 0, 0, 0);
        __syncthreads();
    }
#pragma unroll
    for (int i = 0; i < 4; i++) {
        int mb = m0 + wm + i * 16 + quad * 4;
#pragma unroll
        for (int r = 0; r < 4; r++) {
            int m = mb + r;
            if (m < N_NODES) {
#pragma unroll
                for (int j = 0; j < 4; j++)
                    hbuf[(size_t)m * 128 + wn + j * 16 + l15] = f2b(acc[i][j][r]);
            }
        }
    }
}

// ---------------------------------------------------------------------------
// dinv + counts + scan phase-1 block reduction; LAST block (ticket) also
// scans the 196 block sums (one-shot arrivals, no polling — this pattern
// was bench-proven fine in R2/R3; only POLLING barriers are pathological).
__global__ __launch_bounds__(256) void k_dinv(const unsigned long long* __restrict__ degcnt,
                                              float* __restrict__ dinv,
                                              int* __restrict__ counts,
                                              int* __restrict__ bsum,
                                              int* __restrict__ ticket,
                                              int* __restrict__ bpre,
                                              int* __restrict__ colptr) {
    int i = blockIdx.x * 256 + threadIdx.x;
    int cnt = 0;
    if (i < N_NODES) {
        unsigned long long v = degcnt[i];
        float deg = 1.0f + (float)(unsigned int)(v & 0xffffffffULL) * (1.0f / 8388608.0f);
        dinv[i] = rsqrtf(deg);
        cnt = (int)(v >> 32);
        counts[i] = cnt;
    }
    __shared__ int sh[256];
    __shared__ int s_last;
    sh[threadIdx.x] = cnt;
    __syncthreads();
    for (int ofs = 128; ofs > 0; ofs >>= 1) {
        if (threadIdx.x < ofs) sh[threadIdx.x] += sh[threadIdx.x + ofs];
        __syncthreads();
    }
    if (threadIdx.x == 0) {
        bsum[blockIdx.x] = sh[0];
        __threadfence();
        int t = atomicAdd(ticket, 1);
        s_last = (t == SCAN_BLOCKS - 1) ? 1 : 0;
    }
    __syncthreads();
    if (s_last) {
        __threadfence();
        int t = threadIdx.x;
        int v = (t < SCAN_BLOCKS) ? ((volatile int*)bsum)[t] : 0;
        sh[t] = v;
        __syncthreads();
        for (int ofs = 1; ofs < 256; ofs <<= 1) {
            int u = (t >= ofs) ? sh[t - ofs] : 0;
            __syncthreads();
            sh[t] += u;
            __syncthreads();
        }
        if (t < SCAN_BLOCKS) bpre[t] = sh[t] - v;  // exclusive
        if (t == SCAN_BLOCKS - 1) colptr[N_NODES] = sh[t];
    }
}

__global__ __launch_bounds__(256) void k_scan3(const int* __restrict__ counts,
                                               const int* __restrict__ bpre,
                                               int* __restrict__ colptr) {
    int t = threadIdx.x;
    int i = blockIdx.x * 256 + t;
    int v = (i < N_NODES) ? counts[i] : 0;
    __shared__ int sh[256];
    sh[t] = v;
    __syncthreads();
    for (int ofs = 1; ofs < 256; ofs <<= 1) {
        int u = (t >= ofs) ? sh[t - ofs] : 0;
        __syncthreads();
        sh[t] += u;
        __syncthreads();
    }
    if (i < N_NODES) colptr[i] = bpre[blockIdx.x] + sh[t] - v;
}

// Atomic-free scatter into interleaved (row, norm) records.
__global__ void k_scatter(const int* __restrict__ row, const int* __restrict__ col,
                          const float* __restrict__ ew, const float* __restrict__ dinv,
                          const int* __restrict__ colptr, const int* __restrict__ slot,
                          int2* __restrict__ ern) {
    int e = blockIdx.x * blockDim.x + threadIdx.x;
    if (e < N_EDGES) {
        int c = col[e], r = row[e];
        int p = colptr[c] + slot[e];
        float nrm = dinv[r] * ew[e] * dinv[c];
        ern[p] = make_int2(r, __float_as_int(nrm));
    }
}

// ---------------------------------------------------------------------------
// CSR aggregation: ONE wave per node (12500 blocks) — the R1-proven config
// (2-wave split in R3 was +15-20us/layer: gather is L3-throughput-bound, so
// extra waves only added reduce/sync overhead). 8-edge chunks with next-chunk
// ern broadcast-prefetch.
__global__ __launch_bounds__(256) void k_aggregate(
    const unsigned int* __restrict__ hb, const int* __restrict__ colptr,
    const int2* __restrict__ ern, const float* __restrict__ dinv,
    const float* __restrict__ bias, unsigned int* __restrict__ out, int relu) {
    int node = (blockIdx.x * blockDim.x + threadIdx.x) >> 6;
    int lane = threadIdx.x & 63;
    if (node >= N_NODES) return;
    float di = dinv[node];
    float selfw = di * di;
    unsigned int sv = hb[(size_t)node * 64 + lane];
    float a0 = selfw * blo(sv);
    float a1 = selfw * bhi(sv);
    float c0 = 0.f, c1 = 0.f;
    int start = colptr[node], end = colptr[node + 1];
    int nfull = (end - start) & ~7;
    if (nfull) {
        int e = start;
        int2 rwc[8];
#pragma unroll
        for (int q = 0; q < 8; q++) rwc[q] = ern[e + q];
        for (;;) {
            int en = e + 8;
            bool more = (en < start + nfull);
            int2 rwn[8];
            if (more) {
#pragma unroll
                for (int q = 0; q < 8; q++) rwn[q] = ern[en + q];  // prefetch
            }
            unsigned int v[8];
#pragma unroll
            for (int q = 0; q < 8; q++) v[q] = hb[(size_t)rwc[q].x * 64 + lane];
#pragma unroll
            for (int q = 0; q < 8; q++) {
                float w = __int_as_float(rwc[q].y);
                if (q & 1) { c0 += w * blo(v[q]); c1 += w * bhi(v[q]); }
                else       { a0 += w * blo(v[q]); a1 += w * bhi(v[q]); }
            }
            if (!more) break;
#pragma unroll
            for (int q = 0; q < 8; q++) rwc[q] = rwn[q];
            e = en;
        }
    }
    for (int e = start + nfull; e < end; e++) {
        int2 rw = ern[e];
        float w = __int_as_float(rw.y);
        unsigned int v = hb[(size_t)rw.x * 64 + lane];
        a0 += w * blo(v);
        a1 += w * bhi(v);
    }
    a0 += c0; a1 += c1;
    float2 bv = *(const float2*)&bias[2 * lane];
    a0 += bv.x;
    a1 += bv.y;
    if (relu) { a0 = fmaxf(a0, 0.f); a1 = fmaxf(a1, 0.f); }
    out[(size_t)node * 64 + lane] = pk2(a0, a1);
}

// ---------------------------------------------------------------------------
// BatchNorm stats: per-block partials, atomically folded into sums/sumsq[128].
// (196 blocks -> 196 atomics per address: benign. Per-layer buffers zeroed by
// k_prep_w.)
__global__ __launch_bounds__(256) void k_bnstats(const unsigned int* __restrict__ x,
                                                 float* __restrict__ sums,
                                                 float* __restrict__ sumsq) {
    int u = threadIdx.x & 63;
    int strip = threadIdx.x >> 6;
    int r0 = blockIdx.x * 256;
    int rend = min(r0 + 256, N_NODES);
    float sl = 0.f, s2l = 0.f, sh_ = 0.f, s2h = 0.f;
    for (int r = r0 + strip; r < rend; r += 4) {
        unsigned int v = x[(size_t)r * 64 + u];
        float a = blo(v), b = bhi(v);
        sl += a; s2l += a * a;
        sh_ += b; s2h += b * b;
    }
    __shared__ float buf[4][64][4];
    buf[strip][u][0] = sl; buf[strip][u][1] = s2l;
    buf[strip][u][2] = sh_; buf[strip][u][3] = s2h;
    __syncthreads();
    if (strip == 0) {
#pragma unroll
        for (int s = 1; s < 4; s++) {
            sl += buf[s][u][0]; s2l += buf[s][u][1];
            sh_ += buf[s][u][2]; s2h += buf[s][u][3];
        }
        atomicAdd(&sums[2 * u], sl);
        atomicAdd(&sums[2 * u + 1], sh_);
        atomicAdd(&sumsq[2 * u], s2l);
        atomicAdd(&sumsq[2 * u + 1], s2h);
    }
}

// ---------------------------------------------------------------------------
// Layer-2/3 GEMM: A bf16-packed [M,64 uints], BN scale/shift computed inline
// from raw sums/sumsq in the prologue. K=128, prefetched. No in-kernel
// barriers (R4 evidence: cross-XCD spin barrier cost ~50us).
__global__ __launch_bounds__(256) void k_gemm_h(
    const unsigned int* __restrict__ Ab, const unsigned short* __restrict__ Wt,
    const float* __restrict__ sums, const float* __restrict__ sumsq,
    const float* __restrict__ g, const float* __restrict__ be,
    unsigned short* __restrict__ Out) {
    __shared__ unsigned short As[128][40];
    __shared__ unsigned short Bs[128][40];
    __shared__ float s_sc[128], s_sh[128];
    int tid = threadIdx.x;
    int m0 = blockIdx.x * 128;
    if (tid < 128) {
        const float invn = 1.0f / (float)N_NODES;
        float mu = sums[tid] * invn;
        float var = sumsq[tid] * invn - mu * mu;
        float iv = rsqrtf(var + BN_EPS);
        float sc = g[tid] * iv;
        s_sc[tid] = sc;
        s_sh[tid] = be[tid] - mu * sc;
    }
    __syncthreads();
    int srow = tid >> 1;
    int skh = (tid & 1) << 4;
    int wave = tid >> 6, lane = tid & 63;
    int wm = (wave >> 1) * 64, wn = (wave & 1) * 64;
    int l15 = lane & 15, quad = lane >> 4;
    f32x4 acc[4][4] = {};
    bool arow_ok = (m0 + srow) < N_NODES;
    const unsigned int* arow_b = Ab + (size_t)(m0 + srow) * 64 + (skh >> 1);
    const unsigned short* wrow_p = Wt + (size_t)srow * 128 + skh;
    uint4 r0 = make_uint4(0, 0, 0, 0), r1 = make_uint4(0, 0, 0, 0);
    uint4 tb0, tb1;
    if (arow_ok) {
        r0 = *(const uint4*)(arow_b);
        r1 = *(const uint4*)(arow_b + 4);
    }
    tb0 = *(const uint4*)(wrow_p);
    tb1 = *(const uint4*)(wrow_p + 8);
    for (int kt = 0; kt < 128; kt += 32) {
        unsigned int raw[8] = {r0.x, r0.y, r0.z, r0.w, r1.x, r1.y, r1.z, r1.w};
        unsigned int p[8];
#pragma unroll
        for (int q = 0; q < 8; q++) {
            int ch = kt + skh + 2 * q;
            float f0 = blo(raw[q]) * s_sc[ch] + s_sh[ch];
            float f1 = bhi(raw[q]) * s_sc[ch + 1] + s_sh[ch + 1];
            p[q] = pk2(f0, f1);
        }
        *(uint4*)&As[srow][skh] = make_uint4(p[0], p[1], p[2], p[3]);
        *(uint4*)&As[srow][skh + 8] = make_uint4(p[4], p[5], p[6], p[7]);
        *(uint4*)&Bs[srow][skh] = tb0;
        *(uint4*)&Bs[srow][skh + 8] = tb1;
        __syncthreads();
        if (kt + 32 < 128) {   // prefetch next K-tile under ds_read+MFMA
            if (arow_ok) {
                r0 = *(const uint4*)(arow_b + ((kt + 32) >> 1));
                r1 = *(const uint4*)(arow_b + ((kt + 32) >> 1) + 4);
            }
            tb0 = *(const uint4*)(wrow_p + kt + 32);
            tb1 = *(const uint4*)(wrow_p + kt + 40);
        }
        short8 a[4], b[4];
#pragma unroll
        for (int i = 0; i < 4; i++) a[i] = *(const short8*)&As[wm + i * 16 + l15][quad * 8];
#pragma unroll
        for (int j = 0; j < 4; j++) b[j] = *(const short8*)&Bs[wn + j * 16 + l15][quad * 8];
#pragma unroll
        for (int i = 0; i < 4; i++)
#pragma unroll
            for (int j = 0; j < 4; j++)
                acc[i][j] = __builtin_amdgcn_mfma_f32_16x16x32_bf16(a[i], b[j], acc[i][j], 0, 0, 0);
        __syncthreads();
    }
#pragma unroll
    for (int i = 0; i < 4; i++) {
        int mb = m0 + wm + i * 16 + quad * 4;
#pragma unroll
        for (int r = 0; r < 4; r++) {
            int m = mb + r;
            if (m < N_NODES) {
#pragma unroll
                for (int j = 0; j < 4; j++)
                    Out[(size_t)m * 128 + wn + j * 16 + l15] = f2b(acc[i][j][r]);
            }
        }
    }
}

// ---------------------------------------------------------------------------
// Head: BN3 scale/shift from raw sums (inline), x3 fp32 write, logits+softmax.
__global__ __launch_bounds__(256) void k_logits(const unsigned int* __restrict__ abuf,
                                                const float* __restrict__ sums,
                                                const float* __restrict__ sumsq,
                                                const float* __restrict__ g,
                                                const float* __restrict__ be,
                                                const float* __restrict__ linW,
                                                const float* __restrict__ linb,
                                                float* __restrict__ logits,
                                                float* __restrict__ probs,
                                                float* __restrict__ x3out) {
    __shared__ float Xs[64][130];
    __shared__ float Ws[128 * 40];
    __shared__ float s_sc[128], s_sh[128];
    int tid = threadIdx.x;
    int m0 = blockIdx.x * 64;
    if (tid < 128) {
        const float invn = 1.0f / (float)N_NODES;
        float mu = sums[tid] * invn;
        float var = sumsq[tid] * invn - mu * mu;
        float iv = rsqrtf(var + BN_EPS);
        float sc = g[tid] * iv;
        s_sc[tid] = sc;
        s_sh[tid] = be[tid] - mu * sc;
    }
    for (int q = tid; q < 1280; q += 256)
        *(float4*)&Ws[q * 4] = *(const float4*)&linW[q * 4];
    __syncthreads();
    for (int q = tid; q < 4096; q += 256) {
        int r = q >> 6, u = q & 63;
        int m = m0 + r;
        float f0 = 0.f, f1 = 0.f;
        if (m < N_NODES) {
            unsigned int v = abuf[(size_t)m * 64 + u];
            f0 = blo(v) * s_sc[2 * u] + s_sh[2 * u];
            f1 = bhi(v) * s_sc[2 * u + 1] + s_sh[2 * u + 1];
            *(float2*)&x3out[(size_t)m * 128 + 2 * u] = make_float2(f0, f1);
        }
        *(float2*)&Xs[r][2 * u] = make_float2(f0, f1);
    }
    __syncthreads();
    int r = tid >> 2;
    int cg = tid & 3;
    int cbase = cg * 10;
    float acc[10] = {};
    for (int k = 0; k < 128; k++) {
        float a = Xs[r][k];
#pragma unroll
        for (int j = 0; j < 10; j++) acc[j] += a * Ws[k * 40 + cbase + j];
    }
#pragma unroll
    for (int j = 0; j < 10; j++) acc[j] += linb[cbase + j];
    float m = acc[0];
#pragma unroll
    for (int j = 1; j < 10; j++) m = fmaxf(m, acc[j]);
    m = fmaxf(m, __shfl_xor(m, 1));
    m = fmaxf(m, __shfl_xor(m, 2));
    float ex[10];
    float s = 0.f;
#pragma unroll
    for (int j = 0; j < 10; j++) { ex[j] = expf(acc[j] - m); s += ex[j]; }
    s += __shfl_xor(s, 1);
    s += __shfl_xor(s, 2);
    float inv = 1.0f / s;
    int mrow = m0 + r;
    if (mrow < N_NODES) {
#pragma unroll
        for (int j = 0; j < 10; j += 2) {
            *(float2*)&logits[(size_t)mrow * 40 + cbase + j] = make_float2(acc[j], acc[j + 1]);
            *(float2*)&probs[(size_t)mrow * 40 + cbase + j] = make_float2(ex[j] * inv, ex[j + 1] * inv);
        }
    }
}

// ---------------------------------------------------------------------------
extern "C" void kernel_launch(void* const* d_in, const int* in_sizes, int n_in,
                              void* d_out, int out_size, void* d_ws, size_t ws_size,
                              hipStream_t stream) {
    const float* x = (const float*)d_in[0];
    const unsigned int* eidx = (const unsigned int*)d_in[1];
    const float* ew = (const float*)d_in[2];
    const float* W1 = (const float*)d_in[3];
    const float* b1 = (const float*)d_in[4];
    const float* W2 = (const float*)d_in[5];
    const float* b2 = (const float*)d_in[6];
    const float* W3 = (const float*)d_in[7];
    const float* b3 = (const float*)d_in[8];
    const float* g1 = (const float*)d_in[9];
    const float* be1 = (const float*)d_in[10];
    const float* g2 = (const float*)d_in[11];
    const float* be2 = (const float*)d_in[12];
    const float* g3 = (const float*)d_in[13];
    const float* be3 = (const float*)d_in[14];
    const float* linW = (const float*)d_in[15];
    const float* linb = (const float*)d_in[16];

    float* out = (float*)d_out;
    float* logits = out;
    float* probs = out + (size_t)N_NODES * NCLASS;
    float* x3out = out + 2 * (size_t)N_NODES * NCLASS;

    char* ws = (char*)d_ws;
    size_t off = 0;
    auto take = [&](size_t bytes) -> char* {
        char* p = ws + off;
        off += (bytes + 255) & ~(size_t)255;
        return p;
    };
    int* row32 = (int*)take((size_t)N_EDGES * 4);
    int* col32 = (int*)take((size_t)N_EDGES * 4);
    int* slot = (int*)take((size_t)N_EDGES * 4);
    int* colptr = (int*)take((size_t)(N_NODES + 1) * 4);
    int* counts = (int*)take((size_t)N_NODES * 4);
    unsigned long long* degcnt = (unsigned long long*)take((size_t)N_NODES * 8);
    int2* ern = (int2*)take((size_t)N_EDGES * 8);
    float* dinv = (float*)take((size_t)N_NODES * 4);
    unsigned short* hbuf = (unsigned short*)take((size_t)N_NODES * NHID * 2);
    unsigned short* abuf = (unsigned short*)take((size_t)N_NODES * NHID * 2);
    unsigned short* W1t = (unsigned short*)take((size_t)512 * 128 * 2);
    unsigned short* W2t = (unsigned short*)take((size_t)128 * 128 * 2);
    unsigned short* W3t = (unsigned short*)take((size_t)128 * 128 * 2);
    float* stats = (float*)take(768 * 4);   // [sums1|sumsq1|sums2|sumsq2|sums3|sumsq3]
    int* syncp = (int*)take(8 * 4);         // [0]=dinv ticket
    int* bsum = (int*)take((size_t)SCAN_BLOCKS * 4);
    int* bpre = (int*)take((size_t)SCAN_BLOCKS * 4);
    (void)ws_size; (void)n_in; (void)in_sizes; (void)out_size;

    float* sums1 = stats, *sumsq1 = stats + 128;
    float* sums2 = stats + 256, *sumsq2 = stats + 384;
    float* sums3 = stats + 512, *sumsq3 = stats + 640;

    const int TPB = 256;

    // preprocessing: weights + edge histogram + layer-1 GEMM (separate
    // kernels — the fat fusion congested the GEMM's memory path)
    k_prep_w<<<(98304 + TPB - 1) / TPB, TPB, 0, stream>>>(W1, W2, W3, W1t, W2t, W3t, degcnt, stats, syncp);
    k_edges<<<EDGE_BLOCKS, TPB, 0, stream>>>(eidx, ew, row32, col32, degcnt, slot);
    k_gemm1<<<GEMM1_BLOCKS, TPB, 0, stream>>>(x, W1t, hbuf);
    k_dinv<<<SCAN_BLOCKS, TPB, 0, stream>>>(degcnt, dinv, counts, bsum, &syncp[0], bpre, colptr);
    k_scan3<<<SCAN_BLOCKS, TPB, 0, stream>>>(counts, bpre, colptr);
    k_scatter<<<EDGE_BLOCKS, TPB, 0, stream>>>(row32, col32, ew, dinv, colptr, slot, ern);

    // layer 1
    k_aggregate<<<AGG_BLOCKS, TPB, 0, stream>>>((const unsigned int*)hbuf, colptr, ern, dinv, b1, (unsigned int*)abuf, 1);
    k_bnstats<<<BN_BLOCKS, TPB, 0, stream>>>((const unsigned int*)abuf, sums1, sumsq1);

    // layer 2 (BN1 applied inline in GEMM prologue from raw sums)
    k_gemm_h<<<GEMMH_BLOCKS, TPB, 0, stream>>>((const unsigned int*)abuf, W2t, sums1, sumsq1, g1, be1, hbuf);
    k_aggregate<<<AGG_BLOCKS, TPB, 0, stream>>>((const unsigned int*)hbuf, colptr, ern, dinv, b2, (unsigned int*)abuf, 1);
    k_bnstats<<<BN_BLOCKS, TPB, 0, stream>>>((const unsigned int*)abuf, sums2, sumsq2);

    // layer 3
    k_gemm_h<<<GEMMH_BLOCKS, TPB, 0, stream>>>((const unsigned int*)abuf, W3t, sums2, sumsq2, g2, be2, hbuf);
    k_aggregate<<<AGG_BLOCKS, TPB, 0, stream>>>((const unsigned int*)hbuf, colptr, ern, dinv, b3, (unsigned int*)abuf, 0);
    k_bnstats<<<BN_BLOCKS, TPB, 0, stream>>>((const unsigned int*)abuf, sums3, sumsq3);

    // head: BN3 apply (inline) + x3 write + logits + softmax
    k_logits<<<(N_NODES + 63) / 64, TPB, 0, stream>>>((const unsigned int*)abuf, sums3, sumsq3, g3, be3, linW, linb, logits, probs, x3out);
}

// Round 7
// 452.249 us; speedup vs baseline: 1.5690x; 1.2097x over previous
//
#include <hip/hip_runtime.h>
#include <hip/hip_bf16.h>

#define N_NODES 50000
#define N_EDGES 800000
#define NFEAT 512
#define NHID 128
#define NCLASS 40
#define BN_EPS 1e-5f

typedef __attribute__((ext_vector_type(8))) short short8;
typedef __attribute__((ext_vector_type(4))) float f32x4;

#define GEMM1_BLOCKS ((N_NODES + 127) / 128)   // 391 (BM=128 — proven best)
#define GEMMH_BLOCKS ((N_NODES + 127) / 128)   // 391
#define EDGE_BLOCKS ((N_EDGES + 255) / 256)    // 3125
#define SCAN_BLOCKS ((N_NODES + 255) / 256)    // 196
#define BN_BLOCKS ((N_NODES + 255) / 256)      // 196
#define AGG_BLOCKS ((N_NODES * 64 + 255) / 256) // 12500 (1 wave per node)

__device__ __forceinline__ unsigned short f2b(float f) {
    unsigned int u = __float_as_uint(f);
    u += 0x7fff + ((u >> 16) & 1);   // RTNE
    return (unsigned short)(u >> 16);
}
__device__ __forceinline__ unsigned int pk2(float lo, float hi) {
    unsigned int r;
    asm("v_cvt_pk_bf16_f32 %0, %1, %2" : "=v"(r) : "v"(lo), "v"(hi));
    return r;
}
__device__ __forceinline__ float blo(unsigned int v) {
    return __uint_as_float(v << 16);
}
__device__ __forceinline__ float bhi(unsigned int v) {
    return __uint_as_float(v & 0xffff0000u);
}

// ---------------------------------------------------------------------------
// Weight prep: fp32 W[K][128] -> bf16 W^T[128][K] for W1,W2,W3; zero degcnt,
// stats[768], sync[8].
__global__ void k_prep_w(const float* __restrict__ W1, const float* __restrict__ W2,
                         const float* __restrict__ W3, unsigned short* __restrict__ W1t,
                         unsigned short* __restrict__ W2t, unsigned short* __restrict__ W3t,
                         unsigned long long* __restrict__ degcnt,
                         float* __restrict__ stats, int* __restrict__ syncp) {
    int i = blockIdx.x * blockDim.x + threadIdx.x;
    if (i < N_NODES) degcnt[i] = 0ULL;
    if (i < 768) stats[i] = 0.f;
    else if (i < 776) syncp[i - 768] = 0;
    if (i < 65536) {
        int k = i >> 7, n = i & 127;
        W1t[n * 512 + k] = f2b(W1[i]);
    } else if (i < 81920) {
        int j = i - 65536; int k = j >> 7, n = j & 127;
        W2t[n * 128 + k] = f2b(W2[j]);
    } else if (i < 98304) {
        int j = i - 81920; int k = j >> 7, n = j & 127;
        W3t[n * 128 + k] = f2b(W3[j]);
    }
}

// ---------------------------------------------------------------------------
// FAT kernel (refused — R6's split was a regression: edge work overlaps the
// latency-bound GEMM for free). Blocks [0,391): layer-1 GEMM BM=128 BK=32,
// K=512 with reg prefetch; blocks [391,391+3125): edge convert + histogram.
__global__ __launch_bounds__(256) void k_fat(
    const float* __restrict__ x, const unsigned short* __restrict__ W1t,
    unsigned short* __restrict__ hbuf,
    const unsigned int* __restrict__ words, const float* __restrict__ ew,
    int* __restrict__ row, int* __restrict__ col,
    unsigned long long* __restrict__ degcnt, int* __restrict__ slot) {
    __shared__ unsigned short As[128][40];
    __shared__ unsigned short Bs[128][40];
    __shared__ int s_any;
    int tid = threadIdx.x;
    if (blockIdx.x < GEMM1_BLOCKS) {
        int m0 = blockIdx.x * 128;
        int srow = tid >> 1;
        int skh = (tid & 1) << 4;
        int wave = tid >> 6, lane = tid & 63;
        int wm = (wave >> 1) * 64, wn = (wave & 1) * 64;
        int l15 = lane & 15, quad = lane >> 4;
        f32x4 acc[4][4] = {};
        bool arow_ok = (m0 + srow) < N_NODES;
        const float* arow_p = x + (size_t)(m0 + srow) * 512 + skh;
        const unsigned short* wrow_p = W1t + (size_t)srow * 512 + skh;
        float4 ta[4];
        uint4 tb0, tb1;
#pragma unroll
        for (int q = 0; q < 4; q++) {
            ta[q] = make_float4(0.f, 0.f, 0.f, 0.f);
            if (arow_ok) ta[q] = *(const float4*)(arow_p + q * 4);
        }
        tb0 = *(const uint4*)(wrow_p);
        tb1 = *(const uint4*)(wrow_p + 8);
        for (int kt = 0; kt < 512; kt += 32) {
            unsigned int p[8];
#pragma unroll
            for (int q = 0; q < 4; q++) {
                p[2 * q]     = pk2(ta[q].x, ta[q].y);
                p[2 * q + 1] = pk2(ta[q].z, ta[q].w);
            }
            *(uint4*)&As[srow][skh] = make_uint4(p[0], p[1], p[2], p[3]);
            *(uint4*)&As[srow][skh + 8] = make_uint4(p[4], p[5], p[6], p[7]);
            *(uint4*)&Bs[srow][skh] = tb0;
            *(uint4*)&Bs[srow][skh + 8] = tb1;
            __syncthreads();
            if (kt + 32 < 512) {   // prefetch next K-tile under ds_read+MFMA
#pragma unroll
                for (int q = 0; q < 4; q++) {
                    float4 t4 = make_float4(0.f, 0.f, 0.f, 0.f);
                    if (arow_ok) t4 = *(const float4*)(arow_p + kt + 32 + q * 4);
                    ta[q] = t4;
                }
                tb0 = *(const uint4*)(wrow_p + kt + 32);
                tb1 = *(const uint4*)(wrow_p + kt + 40);
            }
            short8 a[4], b[4];
#pragma unroll
            for (int i = 0; i < 4; i++) a[i] = *(const short8*)&As[wm + i * 16 + l15][quad * 8];
#pragma unroll
            for (int j = 0; j < 4; j++) b[j] = *(const short8*)&Bs[wn + j * 16 + l15][quad * 8];
#pragma unroll
            for (int i = 0; i < 4; i++)
#pragma unroll
                for (int j = 0; j < 4; j++)
                    acc[i][j] = __builtin_amdgcn_mfma_f32_16x16x32_bf16(a[i], b[j], acc[i][j], 0, 0, 0);
            __syncthreads();
        }
#pragma unroll
        for (int i = 0; i < 4; i++) {
            int mb = m0 + wm + i * 16 + quad * 4;
#pragma unroll
            for (int r = 0; r < 4; r++) {
                int m = mb + r;
                if (m < N_NODES) {
#pragma unroll
                    for (int j = 0; j < 4; j++)
                        hbuf[(size_t)m * 128 + wn + j * 16 + l15] = f2b(acc[i][j][r]);
                }
            }
        }
    } else {
        // ---- edge convert + degree histogram (per-block inline detect) ----
        if (tid == 0) s_any = 0;
        __syncthreads();
        unsigned int probe = words[2 * tid + 1];
        if (probe != 0) atomicAdd(&s_any, 1);
        __syncthreads();
        int f = (s_any == 0) ? 1 : 0;  // 1 => int64 layout
        int e = (blockIdx.x - GEMM1_BLOCKS) * 256 + tid;
        if (e < N_EDGES) {
            unsigned int r = f ? words[2 * (size_t)e] : words[e];
            unsigned int c = f ? words[2 * ((size_t)e + N_EDGES)] : words[e + N_EDGES];
            row[e] = (int)r;
            col[e] = (int)c;
            unsigned int q = __float2uint_rn(ew[e] * 8388608.0f);  // 2^23 fixed point
            unsigned long long old = atomicAdd(&degcnt[c], (1ULL << 32) | (unsigned long long)q);
            slot[e] = (int)(old >> 32);
        }
    }
}

// ---------------------------------------------------------------------------
// dinv + counts + scan phase-1 block reduction; LAST block (ticket) also
// scans the 196 block sums (one-shot arrivals, no polling).
__global__ __launch_bounds__(256) void k_dinv(const unsigned long long* __restrict__ degcnt,
                                              float* __restrict__ dinv,
                                              int* __restrict__ counts,
                                              int* __restrict__ bsum,
                                              int* __restrict__ ticket,
                                              int* __restrict__ bpre,
                                              int* __restrict__ colptr) {
    int i = blockIdx.x * 256 + threadIdx.x;
    int cnt = 0;
    if (i < N_NODES) {
        unsigned long long v = degcnt[i];
        float deg = 1.0f + (float)(unsigned int)(v & 0xffffffffULL) * (1.0f / 8388608.0f);
        dinv[i] = rsqrtf(deg);
        cnt = (int)(v >> 32);
        counts[i] = cnt;
    }
    __shared__ int sh[256];
    __shared__ int s_last;
    sh[threadIdx.x] = cnt;
    __syncthreads();
    for (int ofs = 128; ofs > 0; ofs >>= 1) {
        if (threadIdx.x < ofs) sh[threadIdx.x] += sh[threadIdx.x + ofs];
        __syncthreads();
    }
    if (threadIdx.x == 0) {
        bsum[blockIdx.x] = sh[0];
        __threadfence();
        int t = atomicAdd(ticket, 1);
        s_last = (t == SCAN_BLOCKS - 1) ? 1 : 0;
    }
    __syncthreads();
    if (s_last) {
        __threadfence();
        int t = threadIdx.x;
        int v = (t < SCAN_BLOCKS) ? ((volatile int*)bsum)[t] : 0;
        sh[t] = v;
        __syncthreads();
        for (int ofs = 1; ofs < 256; ofs <<= 1) {
            int u = (t >= ofs) ? sh[t - ofs] : 0;
            __syncthreads();
            sh[t] += u;
            __syncthreads();
        }
        if (t < SCAN_BLOCKS) bpre[t] = sh[t] - v;  // exclusive
        if (t == SCAN_BLOCKS - 1) colptr[N_NODES] = sh[t];
    }
}

__global__ __launch_bounds__(256) void k_scan3(const int* __restrict__ counts,
                                               const int* __restrict__ bpre,
                                               int* __restrict__ colptr) {
    int t = threadIdx.x;
    int i = blockIdx.x * 256 + t;
    int v = (i < N_NODES) ? counts[i] : 0;
    __shared__ int sh[256];
    sh[t] = v;
    __syncthreads();
    for (int ofs = 1; ofs < 256; ofs <<= 1) {
        int u = (t >= ofs) ? sh[t - ofs] : 0;
        __syncthreads();
        sh[t] += u;
        __syncthreads();
    }
    if (i < N_NODES) colptr[i] = bpre[blockIdx.x] + sh[t] - v;
}

// Atomic-free scatter into interleaved (row, norm) records.
__global__ void k_scatter(const int* __restrict__ row, const int* __restrict__ col,
                          const float* __restrict__ ew, const float* __restrict__ dinv,
                          const int* __restrict__ colptr, const int* __restrict__ slot,
                          int2* __restrict__ ern) {
    int e = blockIdx.x * blockDim.x + threadIdx.x;
    if (e < N_EDGES) {
        int c = col[e], r = row[e];
        int p = colptr[c] + slot[e];
        float nrm = dinv[r] * ew[e] * dinv[c];
        ern[p] = make_int2(r, __float_as_int(nrm));
    }
}

// ---------------------------------------------------------------------------
// CSR aggregation: ONE wave per node. Every 8-edge round is fully batched —
// OOB slots clamp to a valid address with weight 0, so there is NO serial
// tail (the old <8-edge tail was up to 7 dependent ~600-cycle round-trips,
// dominating the avg-16-edge node's critical path).
__global__ __launch_bounds__(256) void k_aggregate(
    const unsigned int* __restrict__ hb, const int* __restrict__ colptr,
    const int2* __restrict__ ern, const float* __restrict__ dinv,
    const float* __restrict__ bias, unsigned int* __restrict__ out, int relu) {
    int node = (blockIdx.x * blockDim.x + threadIdx.x) >> 6;
    int lane = threadIdx.x & 63;
    if (node >= N_NODES) return;
    float di = dinv[node];
    float selfw = di * di;
    unsigned int sv = hb[(size_t)node * 64 + lane];
    float a0 = selfw * blo(sv);
    float a1 = selfw * bhi(sv);
    float c0 = 0.f, c1 = 0.f;
    int start = colptr[node], end = colptr[node + 1];
    for (int e0 = start; e0 < end; e0 += 8) {
        int2 rw[8];
        float wq[8];
#pragma unroll
        for (int q = 0; q < 8; q++) {
            int ee = e0 + q;
            bool ok = ee < end;
            rw[q] = ern[ok ? ee : start];          // clamped, always valid
            wq[q] = ok ? __int_as_float(rw[q].y) : 0.f;
        }
        unsigned int v[8];
#pragma unroll
        for (int q = 0; q < 8; q++) v[q] = hb[(size_t)rw[q].x * 64 + lane];
#pragma unroll
        for (int q = 0; q < 8; q++) {
            if (q & 1) { c0 += wq[q] * blo(v[q]); c1 += wq[q] * bhi(v[q]); }
            else       { a0 += wq[q] * blo(v[q]); a1 += wq[q] * bhi(v[q]); }
        }
    }
    a0 += c0; a1 += c1;
    float2 bv = *(const float2*)&bias[2 * lane];
    a0 += bv.x;
    a1 += bv.y;
    if (relu) { a0 = fmaxf(a0, 0.f); a1 = fmaxf(a1, 0.f); }
    out[(size_t)node * 64 + lane] = pk2(a0, a1);
}

// ---------------------------------------------------------------------------
// BatchNorm stats: 4-row load batching (old version: 64 SERIAL L2/L3
// round-trips per strip — pure latency). Per-layer buffers zeroed by prep.
__global__ __launch_bounds__(256) void k_bnstats(const unsigned int* __restrict__ x,
                                                 float* __restrict__ sums,
                                                 float* __restrict__ sumsq) {
    int u = threadIdx.x & 63;
    int strip = threadIdx.x >> 6;
    int r0 = blockIdx.x * 256;
    int rend = min(r0 + 256, N_NODES);
    float sl = 0.f, s2l = 0.f, sh_ = 0.f, s2h = 0.f;
    for (int r = r0 + strip; r < rend; r += 16) {
        unsigned int v[4];
#pragma unroll
        for (int k = 0; k < 4; k++) {
            int rr = r + 4 * k;
            v[k] = (rr < rend) ? x[(size_t)rr * 64 + u] : 0u;
        }
#pragma unroll
        for (int k = 0; k < 4; k++) {
            float a = blo(v[k]), b = bhi(v[k]);
            sl += a; s2l += a * a;
            sh_ += b; s2h += b * b;
        }
    }
    __shared__ float buf[4][64][4];
    buf[strip][u][0] = sl; buf[strip][u][1] = s2l;
    buf[strip][u][2] = sh_; buf[strip][u][3] = s2h;
    __syncthreads();
    if (strip == 0) {
#pragma unroll
        for (int s = 1; s < 4; s++) {
            sl += buf[s][u][0]; s2l += buf[s][u][1];
            sh_ += buf[s][u][2]; s2h += buf[s][u][3];
        }
        atomicAdd(&sums[2 * u], sl);
        atomicAdd(&sums[2 * u + 1], sh_);
        atomicAdd(&sumsq[2 * u], s2l);
        atomicAdd(&sumsq[2 * u + 1], s2h);
    }
}

// ---------------------------------------------------------------------------
// Layer-2/3 GEMM: A bf16-packed [M,64 uints], BN scale/shift computed inline
// from raw sums/sumsq in the prologue. K=128, prefetched.
__global__ __launch_bounds__(256) void k_gemm_h(
    const unsigned int* __restrict__ Ab, const unsigned short* __restrict__ Wt,
    const float* __restrict__ sums, const float* __restrict__ sumsq,
    const float* __restrict__ g, const float* __restrict__ be,
    unsigned short* __restrict__ Out) {
    __shared__ unsigned short As[128][40];
    __shared__ unsigned short Bs[128][40];
    __shared__ float s_sc[128], s_sh[128];
    int tid = threadIdx.x;
    int m0 = blockIdx.x * 128;
    if (tid < 128) {
        const float invn = 1.0f / (float)N_NODES;
        float mu = sums[tid] * invn;
        float var = sumsq[tid] * invn - mu * mu;
        float iv = rsqrtf(var + BN_EPS);
        float sc = g[tid] * iv;
        s_sc[tid] = sc;
        s_sh[tid] = be[tid] - mu * sc;
    }
    __syncthreads();
    int srow = tid >> 1;
    int skh = (tid & 1) << 4;
    int wave = tid >> 6, lane = tid & 63;
    int wm = (wave >> 1) * 64, wn = (wave & 1) * 64;
    int l15 = lane & 15, quad = lane >> 4;
    f32x4 acc[4][4] = {};
    bool arow_ok = (m0 + srow) < N_NODES;
    const unsigned int* arow_b = Ab + (size_t)(m0 + srow) * 64 + (skh >> 1);
    const unsigned short* wrow_p = Wt + (size_t)srow * 128 + skh;
    uint4 r0 = make_uint4(0, 0, 0, 0), r1 = make_uint4(0, 0, 0, 0);
    uint4 tb0, tb1;
    if (arow_ok) {
        r0 = *(const uint4*)(arow_b);
        r1 = *(const uint4*)(arow_b + 4);
    }
    tb0 = *(const uint4*)(wrow_p);
    tb1 = *(const uint4*)(wrow_p + 8);
    for (int kt = 0; kt < 128; kt += 32) {
        unsigned int raw[8] = {r0.x, r0.y, r0.z, r0.w, r1.x, r1.y, r1.z, r1.w};
        unsigned int p[8];
#pragma unroll
        for (int q = 0; q < 8; q++) {
            int ch = kt + skh + 2 * q;
            float f0 = blo(raw[q]) * s_sc[ch] + s_sh[ch];
            float f1 = bhi(raw[q]) * s_sc[ch + 1] + s_sh[ch + 1];
            p[q] = pk2(f0, f1);
        }
        *(uint4*)&As[srow][skh] = make_uint4(p[0], p[1], p[2], p[3]);
        *(uint4*)&As[srow][skh + 8] = make_uint4(p[4], p[5], p[6], p[7]);
        *(uint4*)&Bs[srow][skh] = tb0;
        *(uint4*)&Bs[srow][skh + 8] = tb1;
        __syncthreads();
        if (kt + 32 < 128) {   // prefetch next K-tile under ds_read+MFMA
            if (arow_ok) {
                r0 = *(const uint4*)(arow_b + ((kt + 32) >> 1));
                r1 = *(const uint4*)(arow_b + ((kt + 32) >> 1) + 4);
            }
            tb0 = *(const uint4*)(wrow_p + kt + 32);
            tb1 = *(const uint4*)(wrow_p + kt + 40);
        }
        short8 a[4], b[4];
#pragma unroll
        for (int i = 0; i < 4; i++) a[i] = *(const short8*)&As[wm + i * 16 + l15][quad * 8];
#pragma unroll
        for (int j = 0; j < 4; j++) b[j] = *(const short8*)&Bs[wn + j * 16 + l15][quad * 8];
#pragma unroll
        for (int i = 0; i < 4; i++)
#pragma unroll
            for (int j = 0; j < 4; j++)
                acc[i][j] = __builtin_amdgcn_mfma_f32_16x16x32_bf16(a[i], b[j], acc[i][j], 0, 0, 0);
        __syncthreads();
    }
#pragma unroll
    for (int i = 0; i < 4; i++) {
        int mb = m0 + wm + i * 16 + quad * 4;
#pragma unroll
        for (int r = 0; r < 4; r++) {
            int m = mb + r;
            if (m < N_NODES) {
#pragma unroll
                for (int j = 0; j < 4; j++)
                    Out[(size_t)m * 128 + wn + j * 16 + l15] = f2b(acc[i][j][r]);
            }
        }
    }
}

// ---------------------------------------------------------------------------
// Head: BN3 scale/shift from raw sums (inline), x3 fp32 write, logits+softmax.
__global__ __launch_bounds__(256) void k_logits(const unsigned int* __restrict__ abuf,
                                                const float* __restrict__ sums,
                                                const float* __restrict__ sumsq,
                                                const float* __restrict__ g,
                                                const float* __restrict__ be,
                                                const float* __restrict__ linW,
                                                const float* __restrict__ linb,
                                                float* __restrict__ logits,
                                                float* __restrict__ probs,
                                                float* __restrict__ x3out) {
    __shared__ float Xs[64][130];
    __shared__ float Ws[128 * 40];
    __shared__ float s_sc[128], s_sh[128];
    int tid = threadIdx.x;
    int m0 = blockIdx.x * 64;
    if (tid < 128) {
        const float invn = 1.0f / (float)N_NODES;
        float mu = sums[tid] * invn;
        float var = sumsq[tid] * invn - mu * mu;
        float iv = rsqrtf(var + BN_EPS);
        float sc = g[tid] * iv;
        s_sc[tid] = sc;
        s_sh[tid] = be[tid] - mu * sc;
    }
    for (int q = tid; q < 1280; q += 256)
        *(float4*)&Ws[q * 4] = *(const float4*)&linW[q * 4];
    __syncthreads();
    for (int q = tid; q < 4096; q += 256) {
        int r = q >> 6, u = q & 63;
        int m = m0 + r;
        float f0 = 0.f, f1 = 0.f;
        if (m < N_NODES) {
            unsigned int v = abuf[(size_t)m * 64 + u];
            f0 = blo(v) * s_sc[2 * u] + s_sh[2 * u];
            f1 = bhi(v) * s_sc[2 * u + 1] + s_sh[2 * u + 1];
            *(float2*)&x3out[(size_t)m * 128 + 2 * u] = make_float2(f0, f1);
        }
        *(float2*)&Xs[r][2 * u] = make_float2(f0, f1);
    }
    __syncthreads();
    int r = tid >> 2;
    int cg = tid & 3;
    int cbase = cg * 10;
    float acc[10] = {};
    for (int k = 0; k < 128; k++) {
        float a = Xs[r][k];
#pragma unroll
        for (int j = 0; j < 10; j++) acc[j] += a * Ws[k * 40 + cbase + j];
    }
#pragma unroll
    for (int j = 0; j < 10; j++) acc[j] += linb[cbase + j];
    float m = acc[0];
#pragma unroll
    for (int j = 1; j < 10; j++) m = fmaxf(m, acc[j]);
    m = fmaxf(m, __shfl_xor(m, 1));
    m = fmaxf(m, __shfl_xor(m, 2));
    float ex[10];
    float s = 0.f;
#pragma unroll
    for (int j = 0; j < 10; j++) { ex[j] = expf(acc[j] - m); s += ex[j]; }
    s += __shfl_xor(s, 1);
    s += __shfl_xor(s, 2);
    float inv = 1.0f / s;
    int mrow = m0 + r;
    if (mrow < N_NODES) {
#pragma unroll
        for (int j = 0; j < 10; j += 2) {
            *(float2*)&logits[(size_t)mrow * 40 + cbase + j] = make_float2(acc[j], acc[j + 1]);
            *(float2*)&probs[(size_t)mrow * 40 + cbase + j] = make_float2(ex[j] * inv, ex[j + 1] * inv);
        }
    }
}

// ---------------------------------------------------------------------------
extern "C" void kernel_launch(void* const* d_in, const int* in_sizes, int n_in,
                              void* d_out, int out_size, void* d_ws, size_t ws_size,
                              hipStream_t stream) {
    const float* x = (const float*)d_in[0];
    const unsigned int* eidx = (const unsigned int*)d_in[1];
    const float* ew = (const float*)d_in[2];
    const float* W1 = (const float*)d_in[3];
    const float* b1 = (const float*)d_in[4];
    const float* W2 = (const float*)d_in[5];
    const float* b2 = (const float*)d_in[6];
    const float* W3 = (const float*)d_in[7];
    const float* b3 = (const float*)d_in[8];
    const float* g1 = (const float*)d_in[9];
    const float* be1 = (const float*)d_in[10];
    const float* g2 = (const float*)d_in[11];
    const float* be2 = (const float*)d_in[12];
    const float* g3 = (const float*)d_in[13];
    const float* be3 = (const float*)d_in[14];
    const float* linW = (const float*)d_in[15];
    const float* linb = (const float*)d_in[16];

    float* out = (float*)d_out;
    float* logits = out;
    float* probs = out + (size_t)N_NODES * NCLASS;
    float* x3out = out + 2 * (size_t)N_NODES * NCLASS;

    char* ws = (char*)d_ws;
    size_t off = 0;
    auto take = [&](size_t bytes) -> char* {
        char* p = ws + off;
        off += (bytes + 255) & ~(size_t)255;
        return p;
    };
    int* row32 = (int*)take((size_t)N_EDGES * 4);
    int* col32 = (int*)take((size_t)N_EDGES * 4);
    int* slot = (int*)take((size_t)N_EDGES * 4);
    int* colptr = (int*)take((size_t)(N_NODES + 1) * 4);
    int* counts = (int*)take((size_t)N_NODES * 4);
    unsigned long long* degcnt = (unsigned long long*)take((size_t)N_NODES * 8);
    int2* ern = (int2*)take((size_t)N_EDGES * 8);
    float* dinv = (float*)take((size_t)N_NODES * 4);
    unsigned short* hbuf = (unsigned short*)take((size_t)N_NODES * NHID * 2);
    unsigned short* abuf = (unsigned short*)take((size_t)N_NODES * NHID * 2);
    unsigned short* W1t = (unsigned short*)take((size_t)512 * 128 * 2);
    unsigned short* W2t = (unsigned short*)take((size_t)128 * 128 * 2);
    unsigned short* W3t = (unsigned short*)take((size_t)128 * 128 * 2);
    float* stats = (float*)take(768 * 4);   // [sums1|sumsq1|sums2|sumsq2|sums3|sumsq3]
    int* syncp = (int*)take(8 * 4);         // [0]=dinv ticket
    int* bsum = (int*)take((size_t)SCAN_BLOCKS * 4);
    int* bpre = (int*)take((size_t)SCAN_BLOCKS * 4);
    (void)ws_size; (void)n_in; (void)in_sizes; (void)out_size;

    float* sums1 = stats, *sumsq1 = stats + 128;
    float* sums2 = stats + 256, *sumsq2 = stats + 384;
    float* sums3 = stats + 512, *sumsq3 = stats + 640;

    const int TPB = 256;

    // preprocessing + layer-1 GEMM overlapped with edge histogram (fat)
    k_prep_w<<<(98304 + TPB - 1) / TPB, TPB, 0, stream>>>(W1, W2, W3, W1t, W2t, W3t, degcnt, stats, syncp);
    k_fat<<<GEMM1_BLOCKS + EDGE_BLOCKS, TPB, 0, stream>>>(
        x, W1t, hbuf, eidx, ew, row32, col32, degcnt, slot);
    k_dinv<<<SCAN_BLOCKS, TPB, 0, stream>>>(degcnt, dinv, counts, bsum, &syncp[0], bpre, colptr);
    k_scan3<<<SCAN_BLOCKS, TPB, 0, stream>>>(counts, bpre, colptr);
    k_scatter<<<EDGE_BLOCKS, TPB, 0, stream>>>(row32, col32, ew, dinv, colptr, slot, ern);

    // layer 1
    k_aggregate<<<AGG_BLOCKS, TPB, 0, stream>>>((const unsigned int*)hbuf, colptr, ern, dinv, b1, (unsigned int*)abuf, 1);
    k_bnstats<<<BN_BLOCKS, TPB, 0, stream>>>((const unsigned int*)abuf, sums1, sumsq1);

    // layer 2 (BN1 applied inline in GEMM prologue from raw sums)
    k_gemm_h<<<GEMMH_BLOCKS, TPB, 0, stream>>>((const unsigned int*)abuf, W2t, sums1, sumsq1, g1, be1, hbuf);
    k_aggregate<<<AGG_BLOCKS, TPB, 0, stream>>>((const unsigned int*)hbuf, colptr, ern, dinv, b2, (unsigned int*)abuf, 1);
    k_bnstats<<<BN_BLOCKS, TPB, 0, stream>>>((const unsigned int*)abuf, sums2, sumsq2);

    // layer 3
    k_gemm_h<<<GEMMH_BLOCKS, TPB, 0, stream>>>((const unsigned int*)abuf, W3t, sums2, sumsq2, g2, be2, hbuf);
    k_aggregate<<<AGG_BLOCKS, TPB, 0, stream>>>((const unsigned int*)hbuf, colptr, ern, dinv, b3, (unsigned int*)abuf, 0);
    k_bnstats<<<BN_BLOCKS, TPB, 0, stream>>>((const unsigned int*)abuf, sums3, sumsq3);

    // head: BN3 apply (inline) + x3 write + logits + softmax
    k_logits<<<(N_NODES + 63) / 64, TPB, 0, stream>>>((const unsigned int*)abuf, sums3, sumsq3, g3, be3, linW, linb, logits, probs, x3out);
}